// Round 7
// baseline (347.472 us; speedup 1.0000x reference)
//
#include <hip/hip_runtime.h>

// Problem constants: B=8, H=256, W=256, C=8, K=16
// S = B*H*W = 524288 source pixels; out pixel q has 136 channels:
//   ch 0..7 = x[q][ch]
//   ch 8+j  = gauss[k][rem] * x[rem][c],  kc = q>>12 (k=kc>>3, c=kc&7),
//             rem = (q&4095)*128 + j   (j = 0..127)
//
// Two-pass design:
//   pass1: compute gauss[16][S] (each gaussian ONCE) + xT[8][S] into ws.
//   pass2: block b writes out slab of 128 consecutive rows (69.6 KB,
//          monotone block<->offset like the harness fill). PLAIN stores this
//          round (round-4 used nontemporal and sustained only ~2.9 TB/s vs
//          the fill's 6.4 TB/s with plain stores -- NT evict-first is the
//          suspected write-combining killer).
#define S_TOTAL 524288u
#define NEG4LOG2PI (-7.3515082656373808f)

typedef float f32x4 __attribute__((ext_vector_type(4)));

// ---------------- prep: invert lower-triangular L_k, compute base_k ----------------
__global__ void prep_kernel(const float* __restrict__ scale,
                            float* __restrict__ minv,
                            float* __restrict__ base) {
    int k = threadIdx.x;
    if (k >= 16) return;
    float L[8][8], M[8][8];
    const float* Ls = scale + k * 64;
    for (int i = 0; i < 8; i++)
        for (int j = 0; j < 8; j++) { L[i][j] = Ls[i * 8 + j]; M[i][j] = 0.f; }
    for (int j = 0; j < 8; j++) {
        M[j][j] = 1.0f / L[j][j];
        for (int i = j + 1; i < 8; i++) {
            float s = 0.f;
            for (int m = j; m < i; m++) s += L[i][m] * M[m][j];
            M[i][j] = -s / L[i][i];
        }
    }
    float logdet = 0.f;
    for (int i = 0; i < 8; i++) logdet += logf(fabsf(L[i][i]));
    for (int i = 0; i < 8; i++)
        for (int j = 0; j < 8; j++) minv[k * 64 + i * 8 + j] = M[i][j];
    base[k] = -logdet + NEG4LOG2PI;
}

// ---------------- pass1: gauss (once per (k,pixel)) + transposed x ----------------
// grid 512 x 256, 4 consecutive pixels/thread so every ws store is a full
// f32x4 (wave writes 1 KB per store instr). Plain stores: ws stays L2/L3-hot.
__global__ __launch_bounds__(256) void gauss_xt_kernel(
    const float* __restrict__ x,
    const float* __restrict__ minv,
    const float* __restrict__ base,
    const float* __restrict__ mean,
    float* __restrict__ gauss,
    float* __restrict__ xt)
{
    __shared__ float sM[1024];   // 16 x 8x8
    __shared__ float sMu[128];   // 16 x 8
    __shared__ float sB[16];
    for (int i = threadIdx.x; i < 1024; i += 256) sM[i] = minv[i];
    if (threadIdx.x < 128) sMu[threadIdx.x] = mean[threadIdx.x];
    if (threadIdx.x < 16)  sB[threadIdx.x] = base[threadIdx.x];
    __syncthreads();

    const unsigned p0 = (blockIdx.x * 256u + threadIdx.x) * 4u;  // 4 pixels
    float xv[4][8];
    #pragma unroll
    for (int p = 0; p < 4; p++) {
        f32x4 a = ((const f32x4*)x)[(p0 + p) * 2u];
        f32x4 b = ((const f32x4*)x)[(p0 + p) * 2u + 1u];
        xv[p][0] = a.x; xv[p][1] = a.y; xv[p][2] = a.z; xv[p][3] = a.w;
        xv[p][4] = b.x; xv[p][5] = b.y; xv[p][6] = b.z; xv[p][7] = b.w;
    }

    #pragma unroll
    for (int c = 0; c < 8; c++) {
        f32x4 v = {xv[0][c], xv[1][c], xv[2][c], xv[3][c]};
        *(f32x4*)&xt[c * S_TOTAL + p0] = v;
    }

    #pragma unroll
    for (int k = 0; k < 16; k++) {
        const float* M  = &sM[k * 64];
        const float* mu = &sMu[k * 8];
        f32x4 g;
        #pragma unroll
        for (int p = 0; p < 4; p++) {
            float d[8];
            #pragma unroll
            for (int c = 0; c < 8; c++) d[c] = xv[p][c] - mu[c];
            float quad = 0.f;
            #pragma unroll
            for (int i = 0; i < 8; i++) {
                float y = 0.f;
                #pragma unroll
                for (int j = 0; j <= i; j++) y = fmaf(M[i * 8 + j], d[j], y);
                quad = fmaf(y, y, quad);
            }
            g[p] = __expf(fmaf(-0.5f, quad, sB[k]));
        }
        *(f32x4*)&gauss[k * S_TOTAL + p0] = g;
    }
}

// ---------------- pass2: monotone streaming out-sweep (PLAIN stores) ----------------
// grid 4096 x 256. Block b owns 128 consecutive out rows (one kc):
//   kc = b>>5, rows q = kc*4096 + (b&31)*128 + r, r = 0..127.
// 128 rows x 34 f4 = 4352 f4 = 17 exact passes, strictly ascending addresses.
// Reads: gk shared by the 8 blocks +/-32 apart (same XCD under mod-8 dispatch),
// xc shared by blocks 256 apart (same XCD); whole ws is L3-resident.
__global__ __launch_bounds__(256) void out_sweep_kernel(
    const float* __restrict__ x,
    const float* __restrict__ gauss,
    const float* __restrict__ xt,
    float* __restrict__ out)
{
    const unsigned t   = threadIdx.x;
    const unsigned b   = blockIdx.x;          // 0..4095
    const unsigned kc  = b >> 5;              // 0..127
    const unsigned k   = kc >> 3, c = kc & 7u;
    const unsigned rb  = (b & 31u) * 128u;    // r0 base within this kc
    const unsigned q0  = kc * 4096u + rb;     // first out row

    const f32x4* __restrict__ gk = (const f32x4*)(gauss + (size_t)k * S_TOTAL) + rb * 32u;
    const f32x4* __restrict__ xc = (const f32x4*)(xt    + (size_t)c * S_TOTAL) + rb * 32u;
    const f32x4* __restrict__ xh = (const f32x4*)(x + (size_t)q0 * 8u);
    f32x4* __restrict__ o = (f32x4*)(out + (size_t)q0 * 136u);

    #pragma unroll
    for (unsigned pass = 0; pass < 17u; ++pass) {
        unsigned i   = pass * 256u + t;   // 0..4351
        unsigned r   = i / 34u;           // magic-mul
        unsigned ch4 = i - r * 34u;       // 0..33
        f32x4 v;
        if (ch4 < 2u) {
            v = xh[r * 2u + ch4];                       // head: x row verbatim
        } else {
            unsigned idx = r * 32u + (ch4 - 2u);        // 0..4095
            v = gk[idx] * xc[idx];                      // tail: gauss * x[.,c]
        }
        o[i] = v;                                       // plain store, ascending
    }
}

// ---------------- fallback: fused kernel (no workspace needed) ----------------
__global__ __launch_bounds__(256) void fused_kernel(
    const float* __restrict__ x,
    const float* __restrict__ mean,
    const float* __restrict__ scale,
    float* __restrict__ out)
{
    __shared__ float sM[1024];
    __shared__ float sMu[128];
    __shared__ float sB[16];
    __shared__ float sXrT[8][128];
    __shared__ float sGT[16][128];
    __shared__ float sXq[128][8];

    const unsigned t  = threadIdx.x;
    const unsigned r0 = blockIdx.x;

    if (t < 16u) {
        float L[8][8], M[8][8];
        const float* Ls = scale + t * 64u;
        for (int i = 0; i < 8; i++)
            for (int j = 0; j < 8; j++) { L[i][j] = Ls[i * 8 + j]; M[i][j] = 0.f; }
        for (int j = 0; j < 8; j++) {
            M[j][j] = 1.0f / L[j][j];
            for (int i = j + 1; i < 8; i++) {
                float s = 0.f;
                for (int m = j; m < i; m++) s += L[i][m] * M[m][j];
                M[i][j] = -s / L[i][i];
            }
        }
        float logdet = 0.f;
        for (int i = 0; i < 8; i++) logdet += logf(fabsf(L[i][i]));
        for (int i = 0; i < 8; i++)
            for (int j = 0; j < 8; j++) sM[t * 64u + i * 8 + j] = M[i][j];
        sB[t] = -logdet + NEG4LOG2PI;
    }
    if (t < 128u) sMu[t] = mean[t];

    {
        f32x4 v = ((const f32x4*)x)[r0 * 256u + t];
        unsigned p = t >> 1, h = (t & 1u) * 4u;
        sXrT[h + 0][p] = v.x; sXrT[h + 1][p] = v.y;
        sXrT[h + 2][p] = v.z; sXrT[h + 3][p] = v.w;
    }
    {
        unsigned kc = t >> 1, h = t & 1u;
        f32x4 v = ((const f32x4*)x)[(kc * 4096u + r0) * 2u + h];
        unsigned bofs = h * 4u;
        sXq[kc][bofs + 0] = v.x; sXq[kc][bofs + 1] = v.y;
        sXq[kc][bofs + 2] = v.z; sXq[kc][bofs + 3] = v.w;
    }
    __syncthreads();

    {
        unsigned j  = t & 127u;
        unsigned k0 = (t >> 7) * 8u;
        float xv[8];
        #pragma unroll
        for (int c = 0; c < 8; c++) xv[c] = sXrT[c][j];
        #pragma unroll
        for (unsigned kk = 0; kk < 8u; kk++) {
            unsigned k = k0 + kk;
            const float* M  = &sM[k * 64u];
            const float* mu = &sMu[k * 8u];
            float d[8];
            #pragma unroll
            for (int c = 0; c < 8; c++) d[c] = xv[c] - mu[c];
            float quad = 0.f;
            #pragma unroll
            for (int i = 0; i < 8; i++) {
                float y = 0.f;
                #pragma unroll
                for (int jj = 0; jj <= i; jj++) y = fmaf(M[i * 8 + jj], d[jj], y);
                quad = fmaf(y, y, quad);
            }
            sGT[k][j] = __expf(fmaf(-0.5f, quad, sB[k]));
        }
    }
    __syncthreads();

    for (unsigned i = t; i < 4352u; i += 256u) {
        unsigned kc = i / 34u;
        unsigned f4 = i - kc * 34u;
        f32x4 v;
        if (f4 < 2u) {
            v = *(const f32x4*)&sXq[kc][f4 * 4u];
        } else {
            unsigned j0 = f4 * 4u - 8u;
            unsigned k  = kc >> 3, c = kc & 7u;
            f32x4 g  = *(const f32x4*)&sGT[k][j0];
            f32x4 xcv = *(const f32x4*)&sXrT[c][j0];
            v = g * xcv;
        }
        out[(kc * 4096u + r0) * 136u + f4 * 4u + 0] = v.x;
        out[(kc * 4096u + r0) * 136u + f4 * 4u + 1] = v.y;
        out[(kc * 4096u + r0) * 136u + f4 * 4u + 2] = v.z;
        out[(kc * 4096u + r0) * 136u + f4 * 4u + 3] = v.w;
    }
}

extern "C" void kernel_launch(void* const* d_in, const int* in_sizes, int n_in,
                              void* d_out, int out_size, void* d_ws, size_t ws_size,
                              hipStream_t stream) {
    const float* x     = (const float*)d_in[0];
    const float* scale = (const float*)d_in[1];
    const float* mean  = (const float*)d_in[2];
    float* out = (float*)d_out;

    const size_t GAUSS_BYTES = (size_t)16 * S_TOTAL * 4;   // 33.55 MB
    const size_t XT_BYTES    = (size_t)8  * S_TOTAL * 4;   // 16.78 MB
    const size_t NEED = GAUSS_BYTES + XT_BYTES + (1024 + 16) * sizeof(float);

    if (ws_size >= NEED) {
        float* gauss = (float*)d_ws;
        float* xt    = (float*)((char*)d_ws + GAUSS_BYTES);
        float* minv  = (float*)((char*)d_ws + GAUSS_BYTES + XT_BYTES);
        float* base  = minv + 1024;
        prep_kernel<<<1, 64, 0, stream>>>(scale, minv, base);
        gauss_xt_kernel<<<S_TOTAL / 4 / 256, 256, 0, stream>>>(x, minv, base, mean, gauss, xt);
        out_sweep_kernel<<<4096, 256, 0, stream>>>(x, gauss, xt, out);
    } else {
        fused_kernel<<<4096, 256, 0, stream>>>(x, mean, scale, out);
    }
}